// Round 1
// baseline (20.074 us; speedup 1.0000x reference)
//
#include <hip/hip_runtime.h>

#define DIM 10
#define BATCH 65536

__launch_bounds__(256, 1)
__global__ void net_kernel(const float* __restrict__ x,
                           const float* __restrict__ w1,
                           const float* __restrict__ b1,
                           const float* __restrict__ w2,
                           const float* __restrict__ b2,
                           const float* __restrict__ fc1_w,
                           const float* __restrict__ fc1_b,
                           const float* __restrict__ fc2_w,
                           const float* __restrict__ fc2_b,
                           float* __restrict__ out) {
    const int b = blockIdx.x * blockDim.x + threadIdx.x;
    if (b >= BATCH) return;

    // ---- weights (wave-uniform loads -> scalar cache) ----
    float W1[DIM], B1[DIM];
    #pragma unroll
    for (int c = 0; c < DIM; ++c) { W1[c] = w1[c]; B1[c] = b1[c]; }
    float W2[DIM][9];
    #pragma unroll
    for (int c = 0; c < DIM; ++c) {
        #pragma unroll
        for (int k = 0; k < 9; ++k) W2[c][k] = w2[c * 9 + k];
    }
    const float B2 = b2[0];

    // ---- row / col sums of x[b] (vectorized float4 loads) ----
    float row[DIM], col[DIM];
    #pragma unroll
    for (int i = 0; i < DIM; ++i) { row[i] = 0.f; col[i] = 0.f; }
    const float4* xb = reinterpret_cast<const float4*>(x + (size_t)b * (DIM * DIM));
    #pragma unroll
    for (int t = 0; t < 25; ++t) {
        float4 v = xb[t];
        const int e0 = t * 4;
        row[(e0 + 0) / DIM] += v.x; col[(e0 + 0) % DIM] += v.x;
        row[(e0 + 1) / DIM] += v.y; col[(e0 + 1) % DIM] += v.y;
        row[(e0 + 2) / DIM] += v.z; col[(e0 + 2) % DIM] += v.z;
        row[(e0 + 3) / DIM] += v.w; col[(e0 + 3) % DIM] += v.w;
    }

    // ---- conv accumulator (full 10x10 in registers) ----
    float acc[DIM][DIM];
    #pragma unroll
    for (int i = 0; i < DIM; ++i) {
        #pragma unroll
        for (int j = 0; j < DIM; ++j) acc[i][j] = 0.f;
    }

    // For each lower-triangle source pixel (p,q): g[c] = relu(w1[c]*e + b1[c]),
    // s[a*3+b] = sum_c g[c]*W2[c][a*3+b]; scatter s to acc[p+1-a][q+1-b]
    // (cross-correlation, SAME padding -> out[i][j] = sum h[c][i+a-1][j+b-1]*w2[c][a][b]).
    #pragma unroll
    for (int p = 0; p < DIM; ++p) {
        #pragma unroll
        for (int q = 0; q <= p; ++q) {
            const float e = row[p] + col[q];
            float s[9];
            #pragma unroll
            for (int k = 0; k < 9; ++k) s[k] = 0.f;
            #pragma unroll
            for (int c = 0; c < DIM; ++c) {
                const float g = fmaxf(fmaf(W1[c], e, B1[c]), 0.f);
                #pragma unroll
                for (int k = 0; k < 9; ++k) s[k] = fmaf(g, W2[c][k], s[k]);
            }
            #pragma unroll
            for (int a = 0; a < 3; ++a) {
                const int i = p + 1 - a;
                if (i < 0 || i >= DIM) continue;   // compile-time folded
                #pragma unroll
                for (int bb = 0; bb < 3; ++bb) {
                    const int j = q + 1 - bb;
                    if (j < 0 || j >= DIM) continue;
                    acc[i][j] += s[a * 3 + bb];
                }
            }
        }
    }

    // ---- m = relu(acc + b2); v[k] = row-sum_k(m) + col-sum_k(m) ----
    float vsum[DIM];
    #pragma unroll
    for (int k = 0; k < DIM; ++k) vsum[k] = 0.f;
    #pragma unroll
    for (int i = 0; i < DIM; ++i) {
        #pragma unroll
        for (int j = 0; j < DIM; ++j) {
            const float m = fmaxf(acc[i][j] + B2, 0.f);
            vsum[i] += m;
            vsum[j] += m;
        }
    }

    // ---- FC head ----
    float hid[4];
    #pragma unroll
    for (int t = 0; t < 4; ++t) {
        float a = fc1_b[t];
        #pragma unroll
        for (int k = 0; k < DIM; ++k) a = fmaf(vsum[k], fc1_w[t * DIM + k], a);
        hid[t] = fmaxf(a, 0.f);
    }
    float o0 = fc2_b[0], o1 = fc2_b[1];
    #pragma unroll
    for (int t = 0; t < 4; ++t) {
        o0 = fmaf(hid[t], fc2_w[t], o0);
        o1 = fmaf(hid[t], fc2_w[4 + t], o1);
    }
    reinterpret_cast<float2*>(out)[b] = make_float2(o0, o1);
}

extern "C" void kernel_launch(void* const* d_in, const int* in_sizes, int n_in,
                              void* d_out, int out_size, void* d_ws, size_t ws_size,
                              hipStream_t stream) {
    const float* x     = (const float*)d_in[0];
    const float* w1    = (const float*)d_in[1];
    const float* b1    = (const float*)d_in[2];
    const float* w2    = (const float*)d_in[3];
    const float* b2    = (const float*)d_in[4];
    const float* fc1_w = (const float*)d_in[5];
    const float* fc1_b = (const float*)d_in[6];
    const float* fc2_w = (const float*)d_in[7];
    const float* fc2_b = (const float*)d_in[8];
    float* out = (float*)d_out;

    const int block = 256;
    const int grid = BATCH / block;  // 65536 / 256 = 256 blocks
    net_kernel<<<grid, block, 0, stream>>>(x, w1, b1, w2, b2, fc1_w, fc1_b,
                                           fc2_w, fc2_b, out);
}

// Round 2
// 19.493 us; speedup vs baseline: 1.0298x; 1.0298x over previous
//
#include <hip/hip_runtime.h>

#define DIM 10
#define BATCH 65536

// s_k(e) = sum_c W2[c][k] * relu(w1[c]*e + b1[c])  is piecewise-linear in the
// scalar e with 10 shared breakpoints t_c = -b1[c]/w1[c].  Per block we build
// an 11-region table: region r -> s_k = A[r][k]*e + C[r][k]  (k = 0..8).
// Table row layout (20 floats, 80 B, 16B-aligned): [A0..A8, C0..C8, pad, pad].

__launch_bounds__(256, 1)
__global__ void net_kernel(const float* __restrict__ x,
                           const float* __restrict__ w1,
                           const float* __restrict__ b1,
                           const float* __restrict__ w2,
                           const float* __restrict__ b2,
                           const float* __restrict__ fc1_w,
                           const float* __restrict__ fc1_b,
                           const float* __restrict__ fc2_w,
                           const float* __restrict__ fc2_b,
                           float* __restrict__ out) {
    __shared__ float st[10];                       // sorted breakpoints
    __shared__ __align__(16) float tab[11][20];    // [r][A0..A8, C0..C8, pad, pad]

    const int tid = threadIdx.x;
    const int b = blockIdx.x * blockDim.x + tid;

    // ---- issue x loads early (HBM latency overlaps table build) ----
    const float4* xb = reinterpret_cast<const float4*>(x + (size_t)b * (DIM * DIM));
    float4 xv[25];
    #pragma unroll
    for (int t = 0; t < 25; ++t) xv[t] = xb[t];

    // ---- table build part A: breakpoints + ranks (threads 0..9) ----
    if (tid < 10) {
        const float w = w1[tid], bi = b1[tid];
        const float t = (w != 0.0f) ? (-bi / w) : -1e30f;  // w==0: channel is a
                                                           // constant; sentinel
                                                           // keeps it out of range
        int rank = 0;
        #pragma unroll
        for (int c = 0; c < 10; ++c) {
            const float wc = w1[c], bc = b1[c];
            const float tc = (wc != 0.0f) ? (-bc / wc) : -1e30f;
            rank += (c < tid) ? (tc <= t) : (tc < t);      // tie-break by index
        }
        st[rank] = t;
    }

    // ---- row / col sums while wave 0 builds ----
    float row[DIM], col[DIM];
    #pragma unroll
    for (int i = 0; i < DIM; ++i) { row[i] = 0.f; col[i] = 0.f; }
    #pragma unroll
    for (int t = 0; t < 25; ++t) {
        const float4 v = xv[t];
        const int e0 = t * 4;
        row[(e0 + 0) / DIM] += v.x; col[(e0 + 0) % DIM] += v.x;
        row[(e0 + 1) / DIM] += v.y; col[(e0 + 1) % DIM] += v.y;
        row[(e0 + 2) / DIM] += v.z; col[(e0 + 2) % DIM] += v.z;
        row[(e0 + 3) / DIM] += v.w; col[(e0 + 3) % DIM] += v.w;
    }

    __syncthreads();

    // ---- table build part B: A/C per (region, k) (threads 0..98) ----
    if (tid < 99) {
        const int r = tid / 9, k = tid % 9;
        float e_rep;
        if (r == 0)       e_rep = st[0] - 1.0f;
        else if (r == 10) e_rep = st[9] + 1.0f;
        else              e_rep = 0.5f * (st[r - 1] + st[r]);
        float A = 0.f, C = 0.f;
        #pragma unroll
        for (int c = 0; c < 10; ++c) {
            const float w = w1[c], bc = b1[c];
            if (fmaf(w, e_rep, bc) > 0.0f) {
                const float wk = w2[c * 9 + k];
                A = fmaf(wk, w, A);
                C = fmaf(wk, bc, C);
            }
        }
        tab[r][k] = A;
        tab[r][9 + k] = C;
        if (k == 0) { tab[r][18] = 0.f; tab[r][19] = 0.f; }
    }

    __syncthreads();

    // ---- thresholds to registers (broadcast LDS reads) ----
    float th[10];
    #pragma unroll
    for (int i = 0; i < 10; ++i) th[i] = st[i];

    // ---- conv accumulator ----
    float acc[DIM][DIM];
    #pragma unroll
    for (int i = 0; i < DIM; ++i)
        #pragma unroll
        for (int j = 0; j < DIM; ++j) acc[i][j] = 0.f;

    const char* tab_base = reinterpret_cast<const char*>(&tab[0][0]);

    // ---- 55 lower-triangle source pixels ----
    #pragma unroll
    for (int p = 0; p < DIM; ++p) {
        #pragma unroll
        for (int q = 0; q <= p; ++q) {
            const float e = row[p] + col[q];
            // region rank, tree-summed to keep the dep chain short
            const int c0 = e > th[0], c1 = e > th[1], c2 = e > th[2],
                      c3 = e > th[3], c4 = e > th[4], c5 = e > th[5],
                      c6 = e > th[6], c7 = e > th[7], c8 = e > th[8],
                      c9 = e > th[9];
            const int r = ((c0 + c1) + (c2 + c3)) + ((c4 + c5) + (c6 + c7)) + (c8 + c9);
            const float4* trow = reinterpret_cast<const float4*>(tab_base + r * 80);
            const float4 f0 = trow[0], f1 = trow[1], f2 = trow[2],
                         f3 = trow[3], f4 = trow[4];
            const float A[9] = {f0.x, f0.y, f0.z, f0.w, f1.x, f1.y, f1.z, f1.w, f2.x};
            const float C[9] = {f2.y, f2.z, f2.w, f3.x, f3.y, f3.z, f3.w, f4.x, f4.y};
            // scatter: source (p,q) feeds out (p+1-a, q+1-bb) with tap k=a*3+bb
            #pragma unroll
            for (int a = 0; a < 3; ++a) {
                const int i = p + 1 - a;
                if (i < 0 || i >= DIM) continue;          // folds at compile time
                #pragma unroll
                for (int bb = 0; bb < 3; ++bb) {
                    const int j = q + 1 - bb;
                    if (j < 0 || j >= DIM) continue;
                    const int k = a * 3 + bb;
                    acc[i][j] += fmaf(A[k], e, C[k]);
                }
            }
        }
    }

    // ---- m = relu(acc + b2); v[k] = row-sum + col-sum ----
    const float B2 = b2[0];
    float vsum[DIM];
    #pragma unroll
    for (int k = 0; k < DIM; ++k) vsum[k] = 0.f;
    #pragma unroll
    for (int i = 0; i < DIM; ++i) {
        #pragma unroll
        for (int j = 0; j < DIM; ++j) {
            const float m = fmaxf(acc[i][j] + B2, 0.f);
            vsum[i] += m;
            vsum[j] += m;
        }
    }

    // ---- FC head ----
    float hid[4];
    #pragma unroll
    for (int t = 0; t < 4; ++t) {
        float a = fc1_b[t];
        #pragma unroll
        for (int k = 0; k < DIM; ++k) a = fmaf(vsum[k], fc1_w[t * DIM + k], a);
        hid[t] = fmaxf(a, 0.f);
    }
    float o0 = fc2_b[0], o1 = fc2_b[1];
    #pragma unroll
    for (int t = 0; t < 4; ++t) {
        o0 = fmaf(hid[t], fc2_w[t], o0);
        o1 = fmaf(hid[t], fc2_w[4 + t], o1);
    }
    reinterpret_cast<float2*>(out)[b] = make_float2(o0, o1);
}

extern "C" void kernel_launch(void* const* d_in, const int* in_sizes, int n_in,
                              void* d_out, int out_size, void* d_ws, size_t ws_size,
                              hipStream_t stream) {
    const float* x     = (const float*)d_in[0];
    const float* w1    = (const float*)d_in[1];
    const float* b1    = (const float*)d_in[2];
    const float* w2    = (const float*)d_in[3];
    const float* b2    = (const float*)d_in[4];
    const float* fc1_w = (const float*)d_in[5];
    const float* fc1_b = (const float*)d_in[6];
    const float* fc2_w = (const float*)d_in[7];
    const float* fc2_b = (const float*)d_in[8];
    float* out = (float*)d_out;

    const int block = 256;
    const int grid = BATCH / block;  // 256 blocks = 1 per CU
    net_kernel<<<grid, block, 0, stream>>>(x, w1, b1, w2, b2, fc1_w, fc1_b,
                                           fc2_w, fc2_b, out);
}

// Round 3
// 19.290 us; speedup vs baseline: 1.0406x; 1.0105x over previous
//
#include <hip/hip_runtime.h>

#define DIM 10
#define BATCH 65536

typedef float v2f __attribute__((ext_vector_type(2)));

static __device__ __forceinline__ v2f vfma2(v2f a, v2f b, v2f c) {
    return __builtin_elementwise_fma(a, b, c);
}
static __device__ __forceinline__ v2f vmax2(v2f a, v2f b) {
    return __builtin_elementwise_max(a, b);
}

__launch_bounds__(256, 1)
__global__ void net_kernel(const float* __restrict__ x,
                           const float* __restrict__ w1,
                           const float* __restrict__ b1,
                           const float* __restrict__ w2,
                           const float* __restrict__ b2,
                           const float* __restrict__ fc1_w,
                           const float* __restrict__ fc1_b,
                           const float* __restrict__ fc2_w,
                           const float* __restrict__ fc2_b,
                           float* __restrict__ out) {
    // Block tile: 256 elements x 100 floats = 100 KiB, linear (global_load_lds
    // requires contiguous wave-uniform-base + lane*16 destinations).
    __shared__ __align__(16) float xs[256 * DIM * DIM];

    const int tid  = threadIdx.x;
    const int wave = tid >> 6;
    const int lane = tid & 63;
    const size_t blk_elem0 = (size_t)blockIdx.x * 256;

    // ---- Phase 1: coalesced global -> LDS staging ----
    // 100 chunks of 1 KiB (256 floats); wave w issues chunks [25w, 25w+25).
    const float* gbase = x + blk_elem0 * (DIM * DIM);
    #pragma unroll
    for (int i = 0; i < 25; ++i) {
        const int chunk = wave * 25 + i;
        __builtin_amdgcn_global_load_lds(
            (const __attribute__((address_space(1))) void*)(gbase + chunk * 256 + lane * 4),
            (__attribute__((address_space(3))) void*)(xs + chunk * 256),
            16, 0, 0);
    }

    // ---- weights to registers while loads fly (uniform -> scalar loads) ----
    v2f W1p[5], B1p[5];
    #pragma unroll
    for (int cp = 0; cp < 5; ++cp) {
        W1p[cp] = (v2f){w1[2 * cp], w1[2 * cp + 1]};
        B1p[cp] = (v2f){b1[2 * cp], b1[2 * cp + 1]};
    }
    v2f W2p[5][9];
    #pragma unroll
    for (int cp = 0; cp < 5; ++cp)
        #pragma unroll
        for (int k = 0; k < 9; ++k)
            W2p[cp][k] = (v2f){w2[(2 * cp) * 9 + k], w2[(2 * cp + 1) * 9 + k]};
    const float B2 = b2[0];

    __syncthreads();

    // ---- Phase 2: per-thread row/col sums from LDS ----
    float row[DIM], col[DIM];
    #pragma unroll
    for (int i = 0; i < DIM; ++i) { row[i] = 0.f; col[i] = 0.f; }
    const float4* xb = reinterpret_cast<const float4*>(xs + tid * (DIM * DIM));
    #pragma unroll
    for (int t = 0; t < 25; ++t) {
        const float4 v = xb[t];
        const int e0 = t * 4;
        row[(e0 + 0) / DIM] += v.x; col[(e0 + 0) % DIM] += v.x;
        row[(e0 + 1) / DIM] += v.y; col[(e0 + 1) % DIM] += v.y;
        row[(e0 + 2) / DIM] += v.z; col[(e0 + 2) % DIM] += v.z;
        row[(e0 + 3) / DIM] += v.w; col[(e0 + 3) % DIM] += v.w;
    }

    // ---- Phase 3: 55 lower-triangle source pixels, packed-f32 channel math ----
    float acc[DIM][DIM];
    #pragma unroll
    for (int i = 0; i < DIM; ++i)
        #pragma unroll
        for (int j = 0; j < DIM; ++j) acc[i][j] = 0.f;

    #pragma unroll
    for (int p = 0; p < DIM; ++p) {
        #pragma unroll
        for (int q = 0; q <= p; ++q) {
            const float e = row[p] + col[q];
            const v2f e2 = (v2f){e, e};
            v2f s2[9];
            #pragma unroll
            for (int k = 0; k < 9; ++k) s2[k] = (v2f){0.f, 0.f};
            #pragma unroll
            for (int cp = 0; cp < 5; ++cp) {
                const v2f g = vmax2(vfma2(W1p[cp], e2, B1p[cp]), (v2f){0.f, 0.f});
                #pragma unroll
                for (int k = 0; k < 9; ++k) s2[k] = vfma2(g, W2p[cp][k], s2[k]);
            }
            float s[9];
            #pragma unroll
            for (int k = 0; k < 9; ++k) s[k] = s2[k][0] + s2[k][1];
            // scatter: source (p,q) feeds out (p+1-a, q+1-bb), tap k=a*3+bb
            #pragma unroll
            for (int a = 0; a < 3; ++a) {
                const int i = p + 1 - a;
                if (i < 0 || i >= DIM) continue;          // folds at compile time
                #pragma unroll
                for (int bb = 0; bb < 3; ++bb) {
                    const int j = q + 1 - bb;
                    if (j < 0 || j >= DIM) continue;
                    acc[i][j] += s[a * 3 + bb];
                }
            }
        }
    }

    // ---- m = relu(acc + b2); v[k] = row-sum + col-sum ----
    float vsum[DIM];
    #pragma unroll
    for (int k = 0; k < DIM; ++k) vsum[k] = 0.f;
    #pragma unroll
    for (int i = 0; i < DIM; ++i) {
        #pragma unroll
        for (int j = 0; j < DIM; ++j) {
            const float m = fmaxf(acc[i][j] + B2, 0.f);
            vsum[i] += m;
            vsum[j] += m;
        }
    }

    // ---- FC head ----
    float hid[4];
    #pragma unroll
    for (int t = 0; t < 4; ++t) {
        float a = fc1_b[t];
        #pragma unroll
        for (int k = 0; k < DIM; ++k) a = fmaf(vsum[k], fc1_w[t * DIM + k], a);
        hid[t] = fmaxf(a, 0.f);
    }
    float o0 = fc2_b[0], o1 = fc2_b[1];
    #pragma unroll
    for (int t = 0; t < 4; ++t) {
        o0 = fmaf(hid[t], fc2_w[t], o0);
        o1 = fmaf(hid[t], fc2_w[4 + t], o1);
    }
    reinterpret_cast<float2*>(out)[blk_elem0 + tid] = make_float2(o0, o1);
}

extern "C" void kernel_launch(void* const* d_in, const int* in_sizes, int n_in,
                              void* d_out, int out_size, void* d_ws, size_t ws_size,
                              hipStream_t stream) {
    const float* x     = (const float*)d_in[0];
    const float* w1    = (const float*)d_in[1];
    const float* b1    = (const float*)d_in[2];
    const float* w2    = (const float*)d_in[3];
    const float* b2    = (const float*)d_in[4];
    const float* fc1_w = (const float*)d_in[5];
    const float* fc1_b = (const float*)d_in[6];
    const float* fc2_w = (const float*)d_in[7];
    const float* fc2_b = (const float*)d_in[8];
    float* out = (float*)d_out;

    const int block = 256;
    const int grid = BATCH / block;  // 256 blocks = 1 per CU
    net_kernel<<<grid, block, 0, stream>>>(x, w1, b1, w2, b2, fc1_w, fc1_b,
                                           fc2_w, fc2_b, out);
}